// Round 8
// baseline (9766.782 us; speedup 1.0000x reference)
//
#include <hip/hip_runtime.h>
#include <hip/hip_bf16.h>
#include <stdint.h>

// Leaky RNN: v_t = 0.9 v_{t-1} + 0.1 (W_hid fr_{t-1} + b_hid + u_t), fr = relu(v)
// Phase A: u_proj (fp32 tiled GEMM, 128x128, 8x8/thread, conflict-free LDS
//   reads, R6-verified) + b_in + b_hid into d_out in place.
// Phase B: HYBRID exchange scan. 8 WGs x 8 waves (512 thr), 2 WGs per batch
//   group; each wave owns n=32 hid rows (W A-fragments: 128 VGPRs).
//   * OWN half of fr (this WG's 256 rows = 8 kk-tiles): exchanged through LDS
//     with one __syncthreads per step. No tags, no polls. This deletes the
//     32x-redundant global poll traffic on half the data and all its MALL
//     round trips.
//   * PARTNER half (other WG's 8 kk-tiles): the R1-verified tagged protocol,
//     unchanged -- relaxed agent-scope 8B atomics, step-parity tag in the
//     (free, fr>=0) bf16 sign bits, fire-and-forget stores, full-round
//     unconditional polls with one check (R4: branchy polls = 3x slower).
//   Poll round-1 is issued BEFORE the own-half LDS+MFMA block (no data dep)
//   so its flight hides under ~400cy of compute.
// STRUCTURE RULES (R3-R7): linear bid mapping (R3: co-location 1.84x worse);
//   publish immediately after fr + compiler memory barrier (R5: +40% if it
//   sinks); poll rounds stay unconditional+pipelined (R4); u-load placement
//   is a don't-care (R6/R7 neutral).

#define SEQ   1024
#define BATCH 64
#define INDIM 128
#define HID   512
#define HG    16   // total kk-tiles (k-chunks of 32)
#define HKK   8    // kk-tiles per WG (half)
#define BGN   4    // batch groups of 16

typedef __attribute__((ext_vector_type(8))) short   short8;
typedef __attribute__((ext_vector_type(4))) float   floatx4;
typedef unsigned long long ull;

__device__ __forceinline__ unsigned short f2bf(float x) {
  union { float f; unsigned int u; } v; v.f = x;
  unsigned int r = v.u + 0x7fffu + ((v.u >> 16) & 1u);  // RNE
  return (unsigned short)(r >> 16);
}
__device__ __forceinline__ ull pack4(unsigned short a, unsigned short b,
                                     unsigned short c, unsigned short d) {
  return (ull)a | ((ull)b << 16) | ((ull)c << 32) | ((ull)d << 48);
}

// ---------------- Phase A: u_proj = input @ W_in^T + b_in + b_hid -----------
#define TA_SB 128
#define TA_H  128
#define TA_K  64
#define APAD  65

__global__ __launch_bounds__(256) void uproj_kernel(
    const float* __restrict__ inp, const float* __restrict__ Win,
    const float* __restrict__ bin, const float* __restrict__ bhid,
    float* __restrict__ out)
{
  __shared__ float sIn[TA_SB * APAD];
  __shared__ float sW [TA_H  * APAD];
  const int tid = threadIdx.x;
  const int sb0 = (blockIdx.x >> 2) * TA_SB;
  const int h0  = (blockIdx.x & 3) * TA_H;
  const int tx = tid & 15, ty = tid >> 4;

  float acc[8][8];
  #pragma unroll
  for (int i = 0; i < 8; ++i)
    #pragma unroll
    for (int j = 0; j < 8; ++j) acc[i][j] = 0.f;

  for (int kt = 0; kt < INDIM / TA_K; ++kt) {
    #pragma unroll
    for (int p = 0; p < 8; ++p) {
      int idx = tid + 256 * p;                   // 2048 float4 = 128 x 64
      int row = idx >> 4, c4 = (idx & 15) << 2;
      const float4 v = *(const float4*)(inp + (size_t)(sb0 + row) * INDIM + kt * TA_K + c4);
      float* d = sIn + row * APAD + c4;
      d[0] = v.x; d[1] = v.y; d[2] = v.z; d[3] = v.w;
    }
    #pragma unroll
    for (int p = 0; p < 8; ++p) {
      int idx = tid + 256 * p;
      int row = idx >> 4, c4 = (idx & 15) << 2;
      const float4 v = *(const float4*)(Win + (size_t)(h0 + row) * INDIM + kt * TA_K + c4);
      float* d = sW + row * APAD + c4;
      d[0] = v.x; d[1] = v.y; d[2] = v.z; d[3] = v.w;
    }
    __syncthreads();

    for (int k = 0; k < TA_K; ++k) {
      float a[8], b[8];
      #pragma unroll
      for (int i = 0; i < 8; ++i) a[i] = sIn[(ty + 16 * i) * APAD + k];
      #pragma unroll
      for (int j = 0; j < 8; ++j) b[j] = sW[(tx + 16 * j) * APAD + k];  // conflict-free
      #pragma unroll
      for (int i = 0; i < 8; ++i)
        #pragma unroll
        for (int j = 0; j < 8; ++j) acc[i][j] = fmaf(a[i], b[j], acc[i][j]);
    }
    __syncthreads();
  }

  #pragma unroll
  for (int j = 0; j < 8; ++j) {
    float bb = bin[h0 + tx + 16 * j] + bhid[h0 + tx + 16 * j];
    #pragma unroll
    for (int i = 0; i < 8; ++i)
      out[(size_t)(sb0 + ty + 16 * i) * HID + h0 + tx + 16 * j] = acc[i][j] + bb;
  }
}

// ---------------- Phase B: hybrid LDS/global persistent scan ----------------
// Grid 8 x 512. bid = bg*2 + half. Wave idx (tid>>6) in [0,8) owns n-rows
// [half*256 + idx*32, +32) as TWO 16-row blocks b=0,1.
// Global frA (ull units): [slot=2][bg=4][kk=16][q''=8][m=16] = 128 KB, same
// fragment semantics as all previous rounds. WG publishes only its own 8 kk
// (partner polls them); own-half goes through LDS.
// LDS sFr: [slot=2][kk_local=8][m*10 + q''] (pad stride 10 -> 2-way banks,
// 16B-aligned pairs (2q,2q+1) for one ds_read_b128 per kk).
__global__ __launch_bounds__(512, 2) void scan_kernel(
    const float* __restrict__ Whid,
    float* __restrict__ uo,      // d_out: u_proj in, fr out (in place)
    ull* __restrict__ frA)
{
  __shared__ __align__(16) ull sFr[2][HKK][160];   // 20.5 KB

  const int tid  = threadIdx.x;
  const int lane = tid & 63;
  const int idx  = tid >> 6;         // wave 0..7
  const int bid  = blockIdx.x;
  const int bg   = bid >> 1;
  const int half = bid & 1;
  const int b0 = bg * 16;
  const int m  = lane & 15;          // batch col (D col)
  const int q  = lane >> 4;
  const int nA   = half * 256 + idx * 32 + q * 4;  // block0 D rows; block1 +16
  const int naW  = half * 256 + idx * 32 + m;      // A-frag row, block0 (+16 b1)
  const int kkO0 = half * HKK;                     // own kk range base
  const int kkP0 = (1 - half) * HKK;               // partner kk range base
  const int kkpub = kkO0 + idx;                    // the kk this wave publishes

  // ---- one-time: W_hid A-fragments for BOTH 16-row blocks (128 VGPRs) -----
  short8 aw[2][HG];
  #pragma unroll
  for (int b = 0; b < 2; ++b) {
    const float* wrow = Whid + (size_t)(naW + b * 16) * HID + q * 8;
    #pragma unroll
    for (int kk = 0; kk < HG; ++kk) {
      const float4 a = *(const float4*)(wrow + kk * 32);
      const float4 c = *(const float4*)(wrow + kk * 32 + 4);
      union { unsigned short s[8]; short8 v; } u;
      u.s[0] = f2bf(a.x); u.s[1] = f2bf(a.y); u.s[2] = f2bf(a.z); u.s[3] = f2bf(a.w);
      u.s[4] = f2bf(c.x); u.s[5] = f2bf(c.y); u.s[6] = f2bf(c.z); u.s[7] = f2bf(c.w);
      aw[b][kk] = u.v;
    }
  }

  const ull MASKT = 0x8000800080008000ull;
  float v0[4] = {0.f, 0.f, 0.f, 0.f};
  float v1[4] = {0.f, 0.f, 0.f, 0.f};
  const float OMA = 0.9f, AL = 0.1f;

  for (int t = 0; t < SEQ; ++t) {
    // u_t for both blocks (scattered 16B/lane, as in all verified rounds)
    const float* up = uo + ((size_t)t * BATCH + b0 + m) * HID + nA;
    const floatx4 uu0 = *(const floatx4*)(up);
    const floatx4 uu1 = *(const floatx4*)(up + 16);

    floatx4 acc[2][4];
    #pragma unroll
    for (int b = 0; b < 2; ++b)
      #pragma unroll
      for (int j = 0; j < 4; ++j) acc[b][j] = (floatx4){0.f, 0.f, 0.f, 0.f};

    if (t > 0) {
      const int slot = (t - 1) & 1;
      const ull expv = (((t - 1) >> 1) & 1) ? MASKT : 0ull;
      const ull* ap = frA + (size_t)(slot * BGN + bg) * HG * 128
                          + (size_t)kkP0 * 128 + (size_t)(2 * q) * 16 + m;
      ull lo[HKK], hi[HKK];

      // ---- round 1 issue (no dep on own-half compute below) ----
      #pragma unroll
      for (int kkl = 0; kkl < HKK; ++kkl) {
        lo[kkl] = __hip_atomic_load(ap + (size_t)kkl * 128,
                                    __ATOMIC_RELAXED, __HIP_MEMORY_SCOPE_AGENT);
        hi[kkl] = __hip_atomic_load(ap + (size_t)kkl * 128 + 16,
                                    __ATOMIC_RELAXED, __HIP_MEMORY_SCOPE_AGENT);
      }

      // ---- own half from LDS (untagged; barrier-synced) + its MFMAs ----
      // Hides round-1 flight (lgkm domain, no vmcnt dependence).
      #pragma unroll
      for (int kkl = 0; kkl < HKK; ++kkl) {
        union { ull u[2]; short8 s; } bf;
        const ull* p = &sFr[slot][kkl][m * 10 + 2 * q];
        bf.u[0] = p[0]; bf.u[1] = p[1];
        const int kk = kkO0 + kkl;
        acc[0][kk & 3] = __builtin_amdgcn_mfma_f32_16x16x32_bf16(
            aw[0][kk], bf.s, acc[0][kk & 3], 0, 0, 0);
        acc[1][kk & 3] = __builtin_amdgcn_mfma_f32_16x16x32_bf16(
            aw[1][kk], bf.s, acc[1][kk & 3], 0, 0, 0);
      }

      // ---- partner half: sacred poll (full round, one check) ----
      for (;;) {
        int ok = 1;
        #pragma unroll
        for (int kkl = 0; kkl < HKK; ++kkl)
          ok &= (int)(((lo[kkl] & MASKT) == expv) & ((hi[kkl] & MASKT) == expv));
        if (__all(ok)) break;
        #pragma unroll
        for (int kkl = 0; kkl < HKK; ++kkl) {
          lo[kkl] = __hip_atomic_load(ap + (size_t)kkl * 128,
                                      __ATOMIC_RELAXED, __HIP_MEMORY_SCOPE_AGENT);
          hi[kkl] = __hip_atomic_load(ap + (size_t)kkl * 128 + 16,
                                      __ATOMIC_RELAXED, __HIP_MEMORY_SCOPE_AGENT);
        }
      }
      #pragma unroll
      for (int kkl = 0; kkl < HKK; ++kkl) {
        union { ull u[2]; short8 s; } bf;
        bf.u[0] = lo[kkl] & ~MASKT;
        bf.u[1] = hi[kkl] & ~MASKT;
        const int kk = kkP0 + kkl;
        acc[0][kk & 3] = __builtin_amdgcn_mfma_f32_16x16x32_bf16(
            aw[0][kk], bf.s, acc[0][kk & 3], 0, 0, 0);
        acc[1][kk & 3] = __builtin_amdgcn_mfma_f32_16x16x32_bf16(
            aw[1][kk], bf.s, acc[1][kk & 3], 0, 0, 0);
      }
    }

    float fr0[4], fr1[4];
    #pragma unroll
    for (int r = 0; r < 4; ++r) {
      float s0 = acc[0][0][r] + acc[0][1][r] + acc[0][2][r] + acc[0][3][r];
      v0[r] = OMA * v0[r] + AL * (s0 + uu0[r]);
      fr0[r] = fmaxf(v0[r], 0.f);
      float s1 = acc[1][0][r] + acc[1][1][r] + acc[1][2][r] + acc[1][3][r];
      v1[r] = OMA * v1[r] + AL * (s1 + uu1[r]);
      fr1[r] = fmaxf(v1[r], 0.f);
    }

    // ---- publish: global (partner, tagged) FIRST, then LDS (own) ----
    const ull pk0 = pack4(f2bf(fr0[0]), f2bf(fr0[1]), f2bf(fr0[2]), f2bf(fr0[3]));
    const ull pk1 = pack4(f2bf(fr1[0]), f2bf(fr1[1]), f2bf(fr1[2]), f2bf(fr1[3]));
    {
      const ull tg = ((t >> 1) & 1) ? MASKT : 0ull;
      ull* db = frA + (size_t)(((t & 1) * BGN + bg) * HG + kkpub) * 128 + m;
      __hip_atomic_store(db + (size_t)q * 16,       pk0 | tg,
                         __ATOMIC_RELAXED, __HIP_MEMORY_SCOPE_AGENT);
      __hip_atomic_store(db + (size_t)(4 + q) * 16, pk1 | tg,
                         __ATOMIC_RELAXED, __HIP_MEMORY_SCOPE_AGENT);
      asm volatile("" ::: "memory");          // pin publish: no compiler sink
    }
    {
      const int sw = t & 1;
      sFr[sw][idx][m * 10 + q]     = pk0;     // untagged: barrier is the sync
      sFr[sw][idx][m * 10 + 4 + q] = pk1;
    }

    // fp32 output (off critical path)
    float* op = uo + ((size_t)t * BATCH + b0 + m) * HID + nA;
    *(floatx4*)(op)      = (floatx4){fr0[0], fr0[1], fr0[2], fr0[3]};
    *(floatx4*)(op + 16) = (floatx4){fr1[0], fr1[1], fr1[2], fr1[3]};

    __syncthreads();   // own-half slot(t&1) now valid for step t+1
  }
}

// ---------------------------------------------------------------------------
extern "C" void kernel_launch(void* const* d_in, const int* in_sizes, int n_in,
                              void* d_out, int out_size, void* d_ws, size_t ws_size,
                              hipStream_t stream) {
  const float* inp  = (const float*)d_in[0];
  const float* Win  = (const float*)d_in[1];
  const float* bin  = (const float*)d_in[2];
  const float* Whid = (const float*)d_in[3];
  const float* bhid = (const float*)d_in[4];
  float* out = (float*)d_out;

  ull* frA = (ull*)d_ws;   // 128 KB; 0xAA poison reads as tag=1 => invalid early

  uproj_kernel<<<dim3((65536 / TA_SB) * (HID / TA_H)), dim3(256), 0, stream>>>(
      inp, Win, bin, bhid, out);
  scan_kernel<<<dim3(BGN * 2), dim3(512), 0, stream>>>(
      Whid, out, frA);
}

// Round 9
// 2638.616 us; speedup vs baseline: 3.7015x; 3.7015x over previous
//
#include <hip/hip_runtime.h>
#include <hip/hip_bf16.h>
#include <stdint.h>

// Leaky RNN: v_t = 0.9 v_{t-1} + 0.1 (W_hid fr_{t-1} + b_hid + u_t), fr = relu(v)
// Phase A: u_proj (fp32 tiled GEMM, 128x128, 8x8/thread, conflict-free LDS
//   reads, R6-verified) + b_in + b_hid into d_out in place.
// Phase B: HYBRID exchange scan. 8 WGs x 8 waves (512 thr), 2 WGs per batch
//   group; each wave owns n=32 hid rows.
//   * OWN half of fr (this WG's 8 kk-tiles): via LDS + one __syncthreads.
//   * PARTNER half: R1-verified tagged protocol (relaxed agent-scope 8B
//     atomics, parity tag in free sign bits, fire-and-forget, full-round
//     unconditional polls, one check).
// R8 LESSONS (implementation, not concept):
//   * Register arrays must be STATICALLY indexed (rule #20): aw[kkO0+kkl]
//     with runtime kkO0 sent all W fragments to scratch (VGPR=68, 5x slow).
//     Now awO/awP split, every index a static unrolled kkl.
//   * LDS layout must be bank-aware: [m*10+q''] cost 2.6M conflict cycles.
//     Now [kkl][qp][m] ull2: consumer reads byte lane*16 (consecutive b128),
//     producer 8B writes 2-lanes/bank (free).
// STRUCTURE RULES (R3-R7): linear bid mapping; publish immediately after fr
//   + compiler barrier; polls unconditional+pipelined; u placement free.

#define SEQ   1024
#define BATCH 64
#define INDIM 128
#define HID   512
#define HG    16   // total kk-tiles (k-chunks of 32)
#define HKK   8    // kk-tiles per WG half
#define BGN   4    // batch groups of 16

typedef __attribute__((ext_vector_type(8))) short   short8;
typedef __attribute__((ext_vector_type(4))) float   floatx4;
typedef unsigned long long ull;

__device__ __forceinline__ unsigned short f2bf(float x) {
  union { float f; unsigned int u; } v; v.f = x;
  unsigned int r = v.u + 0x7fffu + ((v.u >> 16) & 1u);  // RNE
  return (unsigned short)(r >> 16);
}
__device__ __forceinline__ ull pack4(unsigned short a, unsigned short b,
                                     unsigned short c, unsigned short d) {
  return (ull)a | ((ull)b << 16) | ((ull)c << 32) | ((ull)d << 48);
}

// ---------------- Phase A: u_proj = input @ W_in^T + b_in + b_hid -----------
#define TA_SB 128
#define TA_H  128
#define TA_K  64
#define APAD  65

__global__ __launch_bounds__(256) void uproj_kernel(
    const float* __restrict__ inp, const float* __restrict__ Win,
    const float* __restrict__ bin, const float* __restrict__ bhid,
    float* __restrict__ out)
{
  __shared__ float sIn[TA_SB * APAD];
  __shared__ float sW [TA_H  * APAD];
  const int tid = threadIdx.x;
  const int sb0 = (blockIdx.x >> 2) * TA_SB;
  const int h0  = (blockIdx.x & 3) * TA_H;
  const int tx = tid & 15, ty = tid >> 4;

  float acc[8][8];
  #pragma unroll
  for (int i = 0; i < 8; ++i)
    #pragma unroll
    for (int j = 0; j < 8; ++j) acc[i][j] = 0.f;

  for (int kt = 0; kt < INDIM / TA_K; ++kt) {
    #pragma unroll
    for (int p = 0; p < 8; ++p) {
      int idx = tid + 256 * p;                   // 2048 float4 = 128 x 64
      int row = idx >> 4, c4 = (idx & 15) << 2;
      const float4 v = *(const float4*)(inp + (size_t)(sb0 + row) * INDIM + kt * TA_K + c4);
      float* d = sIn + row * APAD + c4;
      d[0] = v.x; d[1] = v.y; d[2] = v.z; d[3] = v.w;
    }
    #pragma unroll
    for (int p = 0; p < 8; ++p) {
      int idx = tid + 256 * p;
      int row = idx >> 4, c4 = (idx & 15) << 2;
      const float4 v = *(const float4*)(Win + (size_t)(h0 + row) * INDIM + kt * TA_K + c4);
      float* d = sW + row * APAD + c4;
      d[0] = v.x; d[1] = v.y; d[2] = v.z; d[3] = v.w;
    }
    __syncthreads();

    for (int k = 0; k < TA_K; ++k) {
      float a[8], b[8];
      #pragma unroll
      for (int i = 0; i < 8; ++i) a[i] = sIn[(ty + 16 * i) * APAD + k];
      #pragma unroll
      for (int j = 0; j < 8; ++j) b[j] = sW[(tx + 16 * j) * APAD + k];  // conflict-free
      #pragma unroll
      for (int i = 0; i < 8; ++i)
        #pragma unroll
        for (int j = 0; j < 8; ++j) acc[i][j] = fmaf(a[i], b[j], acc[i][j]);
    }
    __syncthreads();
  }

  #pragma unroll
  for (int j = 0; j < 8; ++j) {
    float bb = bin[h0 + tx + 16 * j] + bhid[h0 + tx + 16 * j];
    #pragma unroll
    for (int i = 0; i < 8; ++i)
      out[(size_t)(sb0 + ty + 16 * i) * HID + h0 + tx + 16 * j] = acc[i][j] + bb;
  }
}

// ---------------- Phase B: hybrid LDS/global persistent scan ----------------
// Grid 8 x 512. bid = bg*2 + half. Wave idx (tid>>6) owns rows
// [half*256 + idx*32, +32) = global kk-tile kkpub, as 16-row blocks b=0,1.
// Global frA (ull units): [slot=2][bg=4][kk=16][q''=8][m=16] = 128 KB.
// LDS sFr [slot][kkl][qp=4][m=16] as ull2 (16B): consumer lane reads its
// (2q,2q+1) pair at byte offset lane*16 (consecutive, conflict-free);
// producer lane writes pk0 -> [q>>1][m] half (q&1), pk1 -> [2+(q>>1)][m].
__global__ __launch_bounds__(512, 2) void scan_kernel(
    const float* __restrict__ Whid,
    float* __restrict__ uo,      // d_out: u_proj in, fr out (in place)
    ull* __restrict__ frA)
{
  __shared__ __align__(16) ull sFr[2][HKK][4][16][2];   // 16 KB

  const int tid  = threadIdx.x;
  const int lane = tid & 63;
  const int idx  = tid >> 6;         // wave 0..7
  const int bid  = blockIdx.x;
  const int bg   = bid >> 1;
  const int half = bid & 1;
  const int b0 = bg * 16;
  const int m  = lane & 15;          // batch col (D col)
  const int q  = lane >> 4;
  const int nA   = half * 256 + idx * 32 + q * 4;  // block0 D rows; block1 +16
  const int naW  = half * 256 + idx * 32 + m;      // A-frag row, block0 (+16 b1)
  const int kkO0 = half * HKK;                     // own kk range base
  const int kkP0 = (1 - half) * HKK;               // partner kk range base
  const int kkpub = kkO0 + idx;                    // the kk this wave publishes

  // ---- one-time: W_hid A-fragments, STATICALLY indexed (R8 rule-#20 fix) --
  short8 awO[2][HKK], awP[2][HKK];
  #pragma unroll
  for (int b = 0; b < 2; ++b) {
    const float* wrow = Whid + (size_t)(naW + b * 16) * HID + q * 8;
    #pragma unroll
    for (int kkl = 0; kkl < HKK; ++kkl) {
      {
        const float4 a = *(const float4*)(wrow + (kkO0 + kkl) * 32);
        const float4 c = *(const float4*)(wrow + (kkO0 + kkl) * 32 + 4);
        union { unsigned short s[8]; short8 v; } u;
        u.s[0]=f2bf(a.x); u.s[1]=f2bf(a.y); u.s[2]=f2bf(a.z); u.s[3]=f2bf(a.w);
        u.s[4]=f2bf(c.x); u.s[5]=f2bf(c.y); u.s[6]=f2bf(c.z); u.s[7]=f2bf(c.w);
        awO[b][kkl] = u.v;
      }
      {
        const float4 a = *(const float4*)(wrow + (kkP0 + kkl) * 32);
        const float4 c = *(const float4*)(wrow + (kkP0 + kkl) * 32 + 4);
        union { unsigned short s[8]; short8 v; } u;
        u.s[0]=f2bf(a.x); u.s[1]=f2bf(a.y); u.s[2]=f2bf(a.z); u.s[3]=f2bf(a.w);
        u.s[4]=f2bf(c.x); u.s[5]=f2bf(c.y); u.s[6]=f2bf(c.z); u.s[7]=f2bf(c.w);
        awP[b][kkl] = u.v;
      }
    }
  }

  const ull MASKT = 0x8000800080008000ull;
  float v0[4] = {0.f, 0.f, 0.f, 0.f};
  float v1[4] = {0.f, 0.f, 0.f, 0.f};
  const float OMA = 0.9f, AL = 0.1f;

  for (int t = 0; t < SEQ; ++t) {
    // u_t for both blocks
    const float* up = uo + ((size_t)t * BATCH + b0 + m) * HID + nA;
    const floatx4 uu0 = *(const floatx4*)(up);
    const floatx4 uu1 = *(const floatx4*)(up + 16);

    floatx4 acc[2][4];
    #pragma unroll
    for (int b = 0; b < 2; ++b)
      #pragma unroll
      for (int j = 0; j < 4; ++j) acc[b][j] = (floatx4){0.f, 0.f, 0.f, 0.f};

    if (t > 0) {
      const int slot = (t - 1) & 1;
      const ull expv = (((t - 1) >> 1) & 1) ? MASKT : 0ull;
      const ull* ap = frA + (size_t)(slot * BGN + bg) * HG * 128
                          + (size_t)kkP0 * 128 + (size_t)(2 * q) * 16 + m;
      ull lo[HKK], hi[HKK];

      // ---- round 1 issue (no dep on own-half compute below) ----
      #pragma unroll
      for (int kkl = 0; kkl < HKK; ++kkl) {
        lo[kkl] = __hip_atomic_load(ap + (size_t)kkl * 128,
                                    __ATOMIC_RELAXED, __HIP_MEMORY_SCOPE_AGENT);
        hi[kkl] = __hip_atomic_load(ap + (size_t)kkl * 128 + 16,
                                    __ATOMIC_RELAXED, __HIP_MEMORY_SCOPE_AGENT);
      }

      // ---- own half from LDS (untagged; barrier-synced) + its MFMAs ----
      // lgkm domain: hides round-1 vmem flight.
      #pragma unroll
      for (int kkl = 0; kkl < HKK; ++kkl) {
        union { ull u[2]; short8 s; } bf;
        const ull* p = &sFr[slot][kkl][q][m][0];   // byte offset = lane*16
        bf.u[0] = p[0]; bf.u[1] = p[1];
        acc[0][kkl & 3] = __builtin_amdgcn_mfma_f32_16x16x32_bf16(
            awO[0][kkl], bf.s, acc[0][kkl & 3], 0, 0, 0);
        acc[1][kkl & 3] = __builtin_amdgcn_mfma_f32_16x16x32_bf16(
            awO[1][kkl], bf.s, acc[1][kkl & 3], 0, 0, 0);
      }

      // ---- partner half: sacred poll (full round, one check) ----
      for (;;) {
        int ok = 1;
        #pragma unroll
        for (int kkl = 0; kkl < HKK; ++kkl)
          ok &= (int)(((lo[kkl] & MASKT) == expv) & ((hi[kkl] & MASKT) == expv));
        if (__all(ok)) break;
        #pragma unroll
        for (int kkl = 0; kkl < HKK; ++kkl) {
          lo[kkl] = __hip_atomic_load(ap + (size_t)kkl * 128,
                                      __ATOMIC_RELAXED, __HIP_MEMORY_SCOPE_AGENT);
          hi[kkl] = __hip_atomic_load(ap + (size_t)kkl * 128 + 16,
                                      __ATOMIC_RELAXED, __HIP_MEMORY_SCOPE_AGENT);
        }
      }
      #pragma unroll
      for (int kkl = 0; kkl < HKK; ++kkl) {
        union { ull u[2]; short8 s; } bf;
        bf.u[0] = lo[kkl] & ~MASKT;
        bf.u[1] = hi[kkl] & ~MASKT;
        acc[0][kkl & 3] = __builtin_amdgcn_mfma_f32_16x16x32_bf16(
            awP[0][kkl], bf.s, acc[0][kkl & 3], 0, 0, 0);
        acc[1][kkl & 3] = __builtin_amdgcn_mfma_f32_16x16x32_bf16(
            awP[1][kkl], bf.s, acc[1][kkl & 3], 0, 0, 0);
      }
    }

    float fr0[4], fr1[4];
    #pragma unroll
    for (int r = 0; r < 4; ++r) {
      float s0 = acc[0][0][r] + acc[0][1][r] + acc[0][2][r] + acc[0][3][r];
      v0[r] = OMA * v0[r] + AL * (s0 + uu0[r]);
      fr0[r] = fmaxf(v0[r], 0.f);
      float s1 = acc[1][0][r] + acc[1][1][r] + acc[1][2][r] + acc[1][3][r];
      v1[r] = OMA * v1[r] + AL * (s1 + uu1[r]);
      fr1[r] = fmaxf(v1[r], 0.f);
    }

    // ---- publish: global (partner, tagged) FIRST, then LDS (own) ----
    const ull pk0 = pack4(f2bf(fr0[0]), f2bf(fr0[1]), f2bf(fr0[2]), f2bf(fr0[3]));
    const ull pk1 = pack4(f2bf(fr1[0]), f2bf(fr1[1]), f2bf(fr1[2]), f2bf(fr1[3]));
    {
      const ull tg = ((t >> 1) & 1) ? MASKT : 0ull;
      ull* db = frA + (size_t)(((t & 1) * BGN + bg) * HG + kkpub) * 128 + m;
      __hip_atomic_store(db + (size_t)q * 16,       pk0 | tg,
                         __ATOMIC_RELAXED, __HIP_MEMORY_SCOPE_AGENT);
      __hip_atomic_store(db + (size_t)(4 + q) * 16, pk1 | tg,
                         __ATOMIC_RELAXED, __HIP_MEMORY_SCOPE_AGENT);
      asm volatile("" ::: "memory");          // pin publish: no compiler sink
    }
    {
      const int sw = t & 1;
      sFr[sw][idx][q >> 1][m][q & 1]       = pk0;   // q'' = q
      sFr[sw][idx][2 + (q >> 1)][m][q & 1] = pk1;   // q'' = 4+q
    }

    // fp32 output (off critical path)
    float* op = uo + ((size_t)t * BATCH + b0 + m) * HID + nA;
    *(floatx4*)(op)      = (floatx4){fr0[0], fr0[1], fr0[2], fr0[3]};
    *(floatx4*)(op + 16) = (floatx4){fr1[0], fr1[1], fr1[2], fr1[3]};

    __syncthreads();   // own-half slot(t&1) now valid for step t+1
  }
}

// ---------------------------------------------------------------------------
extern "C" void kernel_launch(void* const* d_in, const int* in_sizes, int n_in,
                              void* d_out, int out_size, void* d_ws, size_t ws_size,
                              hipStream_t stream) {
  const float* inp  = (const float*)d_in[0];
  const float* Win  = (const float*)d_in[1];
  const float* bin  = (const float*)d_in[2];
  const float* Whid = (const float*)d_in[3];
  const float* bhid = (const float*)d_in[4];
  float* out = (float*)d_out;

  ull* frA = (ull*)d_ws;   // 128 KB; 0xAA poison reads as tag=1 => invalid early

  uproj_kernel<<<dim3((65536 / TA_SB) * (HID / TA_H)), dim3(256), 0, stream>>>(
      inp, Win, bin, bhid, out);
  scan_kernel<<<dim3(BGN * 2), dim3(512), 0, stream>>>(
      Whid, out, frA);
}